// Round 15
// baseline (311.325 us; speedup 1.0000x reference)
//
#include <hip/hip_runtime.h>

// Problem constants (match reference)
#define U_NODES 100000
#define I_NODES 50000
#define N_NODES 150000   // U + I
#define EMB_D   64
#define FEAT_K  256
#define N_LAYERS 4

typedef __attribute__((ext_vector_type(8))) short short8;
typedef __attribute__((ext_vector_type(4))) float f32x4;

// f32 -> bf16 round-to-nearest-even (bit trick)
static __device__ __forceinline__ unsigned short f2bf(float f) {
    unsigned u = __builtin_bit_cast(unsigned, f);
    u += 0x7fffu + ((u >> 16) & 1u);
    return (unsigned short)(u >> 16);
}
static __device__ __forceinline__ float bflo(unsigned u) {
    return __builtin_bit_cast(float, u << 16);
}
static __device__ __forceinline__ float bfhi(unsigned u) {
    return __builtin_bit_cast(float, u & 0xffff0000u);
}

// ---------------------------------------------------------------------------
__global__ __launch_bounds__(256) void k_count(const int* __restrict__ col,
                                               int* __restrict__ deg, int E) {
    int e = blockIdx.x * 256 + threadIdx.x;
    if (e < E) atomicAdd(&deg[col[e]], 1);
}

__global__ __launch_bounds__(256) void k_dinv(const int* __restrict__ deg,
                                              float* __restrict__ dinv, int n) {
    int i = blockIdx.x * 256 + threadIdx.x;
    if (i < n) {
        int d = deg[i];
        dinv[i] = (d > 0) ? rsqrtf((float)d) : 0.0f;
    }
}

__global__ __launch_bounds__(256) void k_scan_a(const int* __restrict__ deg,
                                                int* __restrict__ rs,
                                                int* __restrict__ bsum, int n) {
    __shared__ int wsum[4];
    int t = threadIdx.x;
    int i = blockIdx.x * 256 + t;
    int v = (i < n) ? deg[i] : 0;
    int x = v;
    #pragma unroll
    for (int off = 1; off < 64; off <<= 1) {
        int y = __shfl_up(x, off, 64);
        if ((t & 63) >= off) x += y;
    }
    if ((t & 63) == 63) wsum[t >> 6] = x;
    __syncthreads();
    int base = 0;
    #pragma unroll
    for (int w = 0; w < 4; ++w) base += (w < (t >> 6)) ? wsum[w] : 0;
    if (i < n) rs[i] = base + x - v;
    if (t == 255) bsum[blockIdx.x] = base + x;
}

__global__ __launch_bounds__(1024) void k_scan_b(int* __restrict__ bs, int nb) {
    __shared__ int wsum[16];
    int t = threadIdx.x;
    int v = (t < nb) ? bs[t] : 0;
    int x = v;
    #pragma unroll
    for (int off = 1; off < 64; off <<= 1) {
        int y = __shfl_up(x, off, 64);
        if ((t & 63) >= off) x += y;
    }
    if ((t & 63) == 63) wsum[t >> 6] = x;
    __syncthreads();
    int base = 0;
    #pragma unroll
    for (int w = 0; w < 16; ++w) base += (w < (t >> 6)) ? wsum[w] : 0;
    if (t < nb) bs[t] = base + x - v;
}

__global__ __launch_bounds__(256) void k_scan_c(int* __restrict__ rs,
                                                const int* __restrict__ bsum,
                                                int* __restrict__ cursor,
                                                int n, int E) {
    int i = blockIdx.x * 256 + threadIdx.x;
    if (i < n) {
        int v = rs[i] + bsum[blockIdx.x];
        rs[i] = v;
        cursor[i] = v;
    }
    if (i == 0) rs[n] = E;
}

// CSR fill: 4 consecutive edges per thread -> vectorized int4 edge reads and
// FOUR independent (dinv-load -> atomic -> scattered-store) chains in flight
// (R14 model: k_fill is bound by the per-thread serial random-access chain;
// k_count's 1M bare atomics cost <=15 us, the chains cost the other ~45).
__global__ __launch_bounds__(256) void k_fill(const int* __restrict__ row,
                                              const int* __restrict__ col,
                                              const float* __restrict__ dinv,
                                              int* __restrict__ cursor,
                                              int2* __restrict__ csr, int E) {
    int base = (blockIdx.x * 256 + threadIdx.x) * 4;
    if (base >= E) return;
    if (base + 4 <= E) {
        int4 c4 = *(const int4*)(col + base);
        int4 r4 = *(const int4*)(row + base);
        float na = dinv[r4.x] * dinv[c4.x];
        float nb = dinv[r4.y] * dinv[c4.y];
        float nc = dinv[r4.z] * dinv[c4.z];
        float nd = dinv[r4.w] * dinv[c4.w];
        int pa = atomicAdd(&cursor[c4.x], 1);
        int pb = atomicAdd(&cursor[c4.y], 1);
        int pc = atomicAdd(&cursor[c4.z], 1);
        int pd = atomicAdd(&cursor[c4.w], 1);
        int2 va; va.x = r4.x; va.y = __builtin_bit_cast(int, na); csr[pa] = va;
        int2 vb; vb.x = r4.y; vb.y = __builtin_bit_cast(int, nb); csr[pb] = vb;
        int2 vc; vc.x = r4.z; vc.y = __builtin_bit_cast(int, nc); csr[pc] = vc;
        int2 vd; vd.x = r4.w; vd.y = __builtin_bit_cast(int, nd); csr[pd] = vd;
    } else {
        for (int e = base; e < E; ++e) {
            int r = row[e], c = col[e];
            int p = atomicAdd(&cursor[c], 1);
            int2 v; v.x = r; v.y = __builtin_bit_cast(int, dinv[r] * dinv[c]);
            csr[p] = v;
        }
    }
}

// Convert W matrices to bf16 (once per call; 32K elements total)
__global__ __launch_bounds__(256) void k_cvtw(const float* __restrict__ wu,
                                              const float* __restrict__ wi,
                                              unsigned short* __restrict__ wub,
                                              unsigned short* __restrict__ wib) {
    int i = blockIdx.x * 256 + threadIdx.x;
    if (i < EMB_D * FEAT_K) wub[i] = f2bf(wu[i]);
    else                    wib[i - EMB_D * FEAT_K] = f2bf(wi[i - EMB_D * FEAT_K]);
}

// Init: x0 (bf16) = concat(emb_users, emb_items). One thread per 8 elements.
__global__ __launch_bounds__(256) void k_init(const float4* __restrict__ eu,
                                              const float4* __restrict__ ei,
                                              uint4* __restrict__ x,
                                              int n8u, int n8) {
    int i = blockIdx.x * 256 + threadIdx.x;
    if (i >= n8) return;
    const float4* s = (i < n8u) ? (eu + (size_t)i * 2) : (ei + (size_t)(i - n8u) * 2);
    float4 p0 = s[0], p1 = s[1];
    uint4 r;
    r.x = (unsigned)f2bf(p0.x) | ((unsigned)f2bf(p0.y) << 16);
    r.y = (unsigned)f2bf(p0.z) | ((unsigned)f2bf(p0.w) << 16);
    r.z = (unsigned)f2bf(p1.x) | ((unsigned)f2bf(p1.y) << 16);
    r.w = (unsigned)f2bf(p1.z) | ((unsigned)f2bf(p1.w) << 16);
    x[i] = r;
}

// NOTE: macro params use trailing-underscore names (R5 lesson: never collide
// with .x/.y/.z/.w member tokens).
#define ACC8(v_, w_)                       \
    s0 = fmaf(bflo((v_).x), (w_), s0);     \
    s1 = fmaf(bfhi((v_).x), (w_), s1);     \
    s2 = fmaf(bflo((v_).y), (w_), s2);     \
    s3 = fmaf(bfhi((v_).y), (w_), s3);     \
    s4 = fmaf(bflo((v_).z), (w_), s4);     \
    s5 = fmaf(bfhi((v_).z), (w_), s5);     \
    s6 = fmaf(bflo((v_).w), (w_), s6);     \
    s7 = fmaf(bfhi((v_).w), (w_), s7);

// Masked 4-wide gather round: always 4 outstanding gathers; OOB lanes are
// clamped to the last edge with weight zeroed.
#define GATHER4(xsrc_, ep_, em_)                                              \
    {                                                                         \
        int i0_ = (ep_), i1_ = min((ep_) + 1, (em_));                         \
        int i2_ = min((ep_) + 2, (em_)), i3_ = min((ep_) + 3, (em_));         \
        int2 pa_ = csr[i0_], pb_ = csr[i1_], pc_ = csr[i2_], pd_ = csr[i3_];  \
        float wa_ = __builtin_bit_cast(float, pa_.y);                         \
        float wb_ = ((ep_) + 1 <= (em_)) ? __builtin_bit_cast(float, pb_.y) : 0.f; \
        float wc_ = ((ep_) + 2 <= (em_)) ? __builtin_bit_cast(float, pc_.y) : 0.f; \
        float wd_ = ((ep_) + 3 <= (em_)) ? __builtin_bit_cast(float, pd_.y) : 0.f; \
        uint4 va_ = (xsrc_)[(size_t)pa_.x * 8 + lane];                        \
        uint4 vb_ = (xsrc_)[(size_t)pb_.x * 8 + lane];                        \
        uint4 vc_ = (xsrc_)[(size_t)pc_.x * 8 + lane];                        \
        uint4 vd_ = (xsrc_)[(size_t)pd_.x * 8 + lane];                        \
        ACC8(va_, wa_) ACC8(vb_, wb_) ACC8(vc_, wc_) ACC8(vd_, wd_)           \
    }

// Pull-mode aggregation (layers 1..3), bf16 state: 8 lanes/node, 16B/lane.
__global__ __launch_bounds__(256) void k_agg(const uint4* __restrict__ xin,
                                             uint4* __restrict__ xout,
                                             const int* __restrict__ rs,
                                             const int2* __restrict__ csr,
                                             int n_nodes) {
    int idx = blockIdx.x * 256 + threadIdx.x;
    int node = idx >> 3;
    int lane = idx & 7;
    if (node >= n_nodes) return;
    int e0 = rs[node], e1 = rs[node + 1];
    float s0 = 0.f, s1 = 0.f, s2 = 0.f, s3 = 0.f;
    float s4 = 0.f, s5 = 0.f, s6 = 0.f, s7 = 0.f;
    int em = e1 - 1;
    for (int ep = e0; ep < e1; ep += 4) GATHER4(xin, ep, em)
    uint4 r;
    r.x = (unsigned)f2bf(s0) | ((unsigned)f2bf(s1) << 16);
    r.y = (unsigned)f2bf(s2) | ((unsigned)f2bf(s3) << 16);
    r.z = (unsigned)f2bf(s4) | ((unsigned)f2bf(s5) << 16);
    r.w = (unsigned)f2bf(s6) | ((unsigned)f2bf(s7) << 16);
    xout[(size_t)node * 8 + lane] = r;
}

// Layer 4 + fused sum: s = gather(x3); out_row = (emb + x1 + x2 + x3 + s)/25
__global__ __launch_bounds__(256) void k_agg4(const uint4* __restrict__ x3,
                                              const uint4* __restrict__ x1,
                                              const uint4* __restrict__ x2,
                                              const float* __restrict__ embU,
                                              const float* __restrict__ embI,
                                              float* __restrict__ outp,
                                              const int* __restrict__ rs,
                                              const int2* __restrict__ csr,
                                              int n_nodes, int U) {
    int idx = blockIdx.x * 256 + threadIdx.x;
    int node = idx >> 3;
    int lane = idx & 7;
    if (node >= n_nodes) return;
    int e0 = rs[node], e1 = rs[node + 1];
    float s0 = 0.f, s1 = 0.f, s2 = 0.f, s3 = 0.f;
    float s4 = 0.f, s5 = 0.f, s6 = 0.f, s7 = 0.f;
    int em = e1 - 1;
    for (int ep = e0; ep < e1; ep += 4) GATHER4(x3, ep, em)
    uint4 v1 = x1[(size_t)node * 8 + lane];
    uint4 v2 = x2[(size_t)node * 8 + lane];
    uint4 v3 = x3[(size_t)node * 8 + lane];
    const float* ebp = (node < U) ? (embU + (size_t)node * EMB_D)
                                  : (embI + (size_t)(node - U) * EMB_D);
    float4 ea = ((const float4*)ebp)[lane * 2];
    float4 eb2 = ((const float4*)ebp)[lane * 2 + 1];
    const float sc = 1.0f / 25.0f;
    float4 o0, o1;
    o0.x = (ea.x  + bflo(v1.x) + bflo(v2.x) + bflo(v3.x) + s0) * sc;
    o0.y = (ea.y  + bfhi(v1.x) + bfhi(v2.x) + bfhi(v3.x) + s1) * sc;
    o0.z = (ea.z  + bflo(v1.y) + bflo(v2.y) + bflo(v3.y) + s2) * sc;
    o0.w = (ea.w  + bfhi(v1.y) + bfhi(v2.y) + bfhi(v3.y) + s3) * sc;
    o1.x = (eb2.x + bflo(v1.z) + bflo(v2.z) + bflo(v3.z) + s4) * sc;
    o1.y = (eb2.y + bfhi(v1.z) + bfhi(v2.z) + bfhi(v3.z) + s5) * sc;
    o1.z = (eb2.z + bflo(v1.w) + bflo(v2.w) + bflo(v3.w) + s6) * sc;
    o1.w = (eb2.w + bfhi(v1.w) + bfhi(v2.w) + bfhi(v3.w) + s7) * sc;
    float4* op = (float4*)(outp + (size_t)node * EMB_D) + lane * 2;
    op[0] = o0;
    op[1] = o1;
}

// ---------------------------------------------------------------------------
// Projection via MFMA bf16: out[r][c] += (F @ W^T)[r][c]   (sum/25 already in out)
// PIPELINED (R15): persistent blocks (grid=1280 = 5/CU by 32 KB LDS) grid-
// stride ~7 tiles each with DOUBLE-BUFFERED LDS A and counted vmcnt:
//   per iter: STAGE(next -> buf^1); s_waitcnt vmcnt(4)  [NOT 0 — keeps the
//   next tile's 4 loads/wave in flight across the raw s_barrier; oldest-first
//   retirement drains epilogue+cur exactly]; raw barrier; COMPUTE(cur);
//   lgkmcnt(0); raw barrier; swap.
// R14 lesson: one-shot blocks paid naked full HBM latency per 16 KB tile ->
// stuck at 2.1 TB/s across three structures. This is the m201/T3+T4 pattern.
// Fragment layouts (16x16x32 bf16, m89/m91-verified):
//   A: row = l&15, k = (l>>4)*8 + j ;  B: col = l&15, k = (l>>4)*8 + j
//   D: col = l&15, row = (l>>4)*4 + reg
#define PROJ_GRID 1280

__device__ __forceinline__ void proj_stage(const float* __restrict__ FU,
                                           const float* __restrict__ FI,
                                           int nbU, int U, int I, int t,
                                           float* dst, int wave, int lane) {
    bool su = t < nbU;
    const float* F = su ? FU : FI;
    int tl = su ? t : t - nbU;
    int M  = su ? U : I;
    int r0 = tl * 16;
    #pragma unroll
    for (int j = 0; j < 4; ++j) {
        int r = wave * 4 + j;
        int g = min(r0 + r, M - 1);
        int sb = (lane * 16) ^ ((r & 7) << 4);   // pre-swizzled source (rule #21)
        const float* src = F + (size_t)g * FEAT_K + (sb >> 2);
        __builtin_amdgcn_global_load_lds(
            (const __attribute__((address_space(1))) void*)src,
            (__attribute__((address_space(3))) void*)(dst + r * 256),
            16, 0, 0);
    }
}

__global__ __launch_bounds__(256) void k_projm(const float* __restrict__ FU,
                                               const float* __restrict__ FI,
                                               const unsigned short* __restrict__ WUb,
                                               const unsigned short* __restrict__ WIb,
                                               float* __restrict__ out,
                                               int nbU, int U, int I, int nT) {
    __shared__ float sA[2][16 * 256];   // 2 x 16 KB double buffer
    const int wave = threadIdx.x >> 6;
    const int lane = threadIdx.x & 63;
    const int l15  = lane & 15;
    const int kq   = lane >> 4;
    const int sw   = (l15 & 7) << 4;

    int t = blockIdx.x;
    // prologue: stage first tile into buf 0; B regs for its side
    proj_stage(FU, FI, nbU, U, I, t, sA[0], wave, lane);
    bool curU = (t < nbU);
    const uint4* wp = (curU ? (const uint4*)WUb : (const uint4*)WIb)
                      + (size_t)(wave * 16 + l15) * 32 + kq;
    uint4 B0 = wp[0],  B1 = wp[4],  B2 = wp[8],  B3 = wp[12];
    uint4 B4 = wp[16], B5 = wp[20], B6 = wp[24], B7 = wp[28];

    int buf = 0;
    for (; t < nT; t += PROJ_GRID) {
        int tn = t + PROJ_GRID;
        if (tn < nT) {
            proj_stage(FU, FI, nbU, U, I, tn, sA[buf ^ 1], wave, lane);
            asm volatile("s_waitcnt vmcnt(4)" ::: "memory");
        } else {
            asm volatile("s_waitcnt vmcnt(0)" ::: "memory");
        }
        __builtin_amdgcn_sched_barrier(0);
        __builtin_amdgcn_s_barrier();
        __builtin_amdgcn_sched_barrier(0);

        // B side switch (wave-uniform; at most once per block)
        bool u = (t < nbU);
        if (u != curU) {
            const uint4* wq = (u ? (const uint4*)WUb : (const uint4*)WIb)
                              + (size_t)(wave * 16 + l15) * 32 + kq;
            B0 = wq[0];  B1 = wq[4];  B2 = wq[8];  B3 = wq[12];
            B4 = wq[16]; B5 = wq[20]; B6 = wq[24]; B7 = wq[28];
            curU = u;
        }

        // compute tile t from sA[buf]
        {
            bool su = u;
            float* o = su ? out : out + (size_t)U * EMB_D;
            int tl = su ? t : t - nbU;
            int M  = su ? U : I;
            int r0 = tl * 16;
            f32x4 acc = {0.f, 0.f, 0.f, 0.f};
            const char* ap = (const char*)(sA[buf] + l15 * 256);

#define CVT2(d_, lo_, hi_) asm("v_cvt_pk_bf16_f32 %0, %1, %2" : "=v"(d_) : "v"(lo_), "v"(hi_))
#define KS(ks_, B_)                                                            \
    {                                                                          \
        int cb = (ks_) * 128 + kq * 32;                                        \
        f32x4 lo = *(const f32x4*)(ap + ((cb) ^ sw));                          \
        f32x4 hi = *(const f32x4*)(ap + ((cb + 16) ^ sw));                     \
        unsigned p0, p1, p2, p3;                                               \
        CVT2(p0, lo[0], lo[1]); CVT2(p1, lo[2], lo[3]);                        \
        CVT2(p2, hi[0], hi[1]); CVT2(p3, hi[2], hi[3]);                        \
        uint4 up; up.x = p0; up.y = p1; up.z = p2; up.w = p3;                  \
        short8 av = __builtin_bit_cast(short8, up);                            \
        short8 bv = __builtin_bit_cast(short8, B_);                            \
        acc = __builtin_amdgcn_mfma_f32_16x16x32_bf16(av, bv, acc, 0, 0, 0);   \
    }
            KS(0, B0) KS(1, B1) KS(2, B2) KS(3, B3)
            KS(4, B4) KS(5, B5) KS(6, B6) KS(7, B7)
#undef KS
#undef CVT2

            #pragma unroll
            for (int r = 0; r < 4; ++r) {
                int grow = r0 + kq * 4 + r;
                if (grow < M) {
                    float* op = o + (size_t)grow * EMB_D + wave * 16 + l15;
                    op[0] += acc[r];
                }
            }
        }

        __builtin_amdgcn_sched_barrier(0);
        asm volatile("s_waitcnt lgkmcnt(0)" ::: "memory");
        __builtin_amdgcn_s_barrier();
        __builtin_amdgcn_sched_barrier(0);
        buf ^= 1;
    }
}

// ---------------------------------------------------------------------------
extern "C" void kernel_launch(void* const* d_in, const int* in_sizes, int n_in,
                              void* d_out, int out_size, void* d_ws, size_t ws_size,
                              hipStream_t stream) {
    const int E = in_sizes[0] / 2;
    const int N = N_NODES, U = U_NODES;

    const int*   edge  = (const int*)d_in[0];
    const float* emb_u = (const float*)d_in[1];
    const float* emb_i = (const float*)d_in[2];
    const float* fu    = (const float*)d_in[3];
    const float* fi    = (const float*)d_in[4];
    const float* wu    = (const float*)d_in[5];
    const float* wi    = (const float*)d_in[6];
    const int* row = edge;
    const int* col = edge + E;

    const int NB  = (N + 255) / 256;
    const int EB  = (E + 255) / 256;
    const int XB8 = ((N * 8) + 255) / 256;

    // Workspace carve (aligned 256B). ~88 MB total.
    char* p = (char*)d_ws;
    auto carve = [&](size_t bytes) -> void* {
        void* q = (void*)p;
        p += (bytes + 255) & ~(size_t)255;
        return q;
    };
    float* dinv    = (float*)carve((size_t)N * 4);
    int*   deg     = (int*)  carve((size_t)N * 4);
    int*   rs      = (int*)  carve((size_t)(N + 1) * 4);
    int*   cursor  = (int*)  carve((size_t)N * 4);
    int*   bsum    = (int*)  carve(1024 * 4);
    int2*  csr     = (int2*) carve((size_t)E * 8);      // packed (src, norm)
    unsigned short* wub = (unsigned short*)carve((size_t)EMB_D * FEAT_K * 2);
    unsigned short* wib = (unsigned short*)carve((size_t)EMB_D * FEAT_K * 2);
    uint4* x0 = (uint4*)carve((size_t)N * EMB_D * 2);   // bf16 layer states
    uint4* x1 = (uint4*)carve((size_t)N * EMB_D * 2);
    uint4* x2 = (uint4*)carve((size_t)N * EMB_D * 2);
    uint4* x3 = (uint4*)carve((size_t)N * EMB_D * 2);

    float* outp = (float*)d_out;   // [N][64] == [u_final; i_final]

    hipMemsetAsync(deg, 0, (size_t)N * 4, stream);
    k_count<<<EB, 256, 0, stream>>>(col, deg, E);
    k_dinv<<<NB, 256, 0, stream>>>(deg, dinv, N);
    k_scan_a<<<NB, 256, 0, stream>>>(deg, rs, bsum, N);
    k_scan_b<<<1, 1024, 0, stream>>>(bsum, NB);
    k_scan_c<<<NB, 256, 0, stream>>>(rs, bsum, cursor, N, E);
    k_fill<<<(E / 4 + 255) / 256, 256, 0, stream>>>(row, col, dinv, cursor, csr, E);
    k_cvtw<<<(2 * EMB_D * FEAT_K) / 256, 256, 0, stream>>>(wu, wi, wub, wib);
    k_init<<<XB8, 256, 0, stream>>>((const float4*)emb_u, (const float4*)emb_i,
                                    x0, U * 8, N * 8);
    // layers 1..3: pure propagation, bf16 state
    k_agg<<<XB8, 256, 0, stream>>>(x0, x1, rs, csr, N);
    k_agg<<<XB8, 256, 0, stream>>>(x1, x2, rs, csr, N);
    k_agg<<<XB8, 256, 0, stream>>>(x2, x3, rs, csr, N);
    // layer 4 fused with the (x0..x4) sum and 1/25 scale -> d_out
    k_agg4<<<XB8, 256, 0, stream>>>(x3, x1, x2, emb_u, emb_i, outp, rs, csr, N, U);
    // projection: out += F @ W^T (persistent pipelined; 16-row tiles)
    const int nbU = (U + 15) / 16;               // 6250
    const int nbI = (N - U + 15) / 16;           // 3125
    k_projm<<<PROJ_GRID, 256, 0, stream>>>(fu, fi, wub, wib, outp,
                                           nbU, U, N - U, nbU + nbI);
}